// Round 5
// baseline (18328.983 us; speedup 1.0000x reference)
//
#include <hip/hip_runtime.h>
#include <hip/hip_bf16.h>

// TemporalDecoder: B=2048, LATENT=128, HIDDEN=512, DEPTH=2, NUMF=128, T=128
// Round 5 (= R4 resubmit; two acquisition timeouts, hypothesis untested):
// ONE persistent cooperative kernel for all 128 steps (3 phases/step: L0 GRU,
// L1 GRU, outproj), hand-rolled 2-level grid barrier with agent-scope fences.
// If cooperative launch is rejected, fall back to the R2 per-step multi-kernel
// path (same device code, identical numerics).

using bf16 = __hip_bfloat16;
typedef __attribute__((ext_vector_type(8))) short short8;  // 8 bf16
typedef __attribute__((ext_vector_type(4))) float f32x4;

#define MFMA(a, b, c) __builtin_amdgcn_mfma_f32_16x16x32_bf16((a), (b), (c), 0, 0, 0)

#define OFF_U 33554432
#define OFF_M 33816576
#define OFF_S 67371008

__device__ __forceinline__ void gld16(const void* g, void* l) {
  __builtin_amdgcn_global_load_lds(
      (const __attribute__((address_space(1))) unsigned int*)g,
      (__attribute__((address_space(3))) unsigned int*)l, 16, 0, 0);
}

__device__ __forceinline__ float sigm(float x) { return 1.f / (1.f + __expf(-x)); }

// Read a 16x32 MFMA fragment from a swizzled LDS tile ([rows][rowbytes],
// phys = logical ^ ((row&7)<<4)).
__device__ __forceinline__ short8 frag_ld(const char* tile, int r0, int kk, int lane, int rowbytes) {
  int row = r0 + (lane & 15);
  int off = row * rowbytes + ((kk + ((lane >> 4) << 3)) << 1);
  off ^= (row & 7) << 4;
  return *(const short8*)(tile + off);
}

// Stage one 1KB chunk (8 rows x 128B) global->LDS, inverse-swizzled source.
__device__ __forceinline__ void stage_rows(const char* src_base, int ldb, int kbyte,
                                           int row0, char* dst, int lane) {
  int r = lane >> 3;
  int l = ((lane & 7) ^ r) << 4;
  gld16(src_base + (size_t)(row0 + r) * ldb + kbyte + l, dst);
}

// ------------------------------- setup kernels -----------------------------
__global__ void cvtk(const float* __restrict__ s, bf16* __restrict__ d, int n) {
  int i = blockIdx.x * 256 + threadIdx.x;
  if (i < n) d[i] = __float2bfloat16(s[i]);
}

__global__ void initk(int* a, int* l, unsigned* bar) {
  int i = blockIdx.x * 256 + threadIdx.x;
  a[i] = 1;
  l[i] = 0;
  if (i < 512) bar[i] = 0;
}

__global__ void e_fill(const float* __restrict__ e, bf16* __restrict__ x0a,
                       bf16* __restrict__ x0b) {
  int i = blockIdx.x * 256 + threadIdx.x;  // 2048*128
  int r = i >> 7, c = i & 127;
  bf16 v = __float2bfloat16(e[i]);
  x0a[r * 640 + c] = v;
  x0b[r * 640 + c] = v;
}

__global__ void catk(const float* __restrict__ wih, const float* __restrict__ whh,
                     bf16* __restrict__ dst, int kx, int total) {
  int i = blockIdx.x * 256 + threadIdx.x;
  if (i >= total) return;
  int ktot = kx + 512;
  int r = i / ktot, c = i - r * ktot;
  float v = (c < kx) ? wih[r * kx + c] : whh[r * 512 + (c - kx)];
  dst[i] = __float2bfloat16(v);
}

// Setup GEMM (fc1/fc2 only), as R2.
template <int MODE>
__global__ __launch_bounds__(256) void gemm_plain(
    const bf16* __restrict__ A, const bf16* __restrict__ Bw,
    const float* __restrict__ bias,
    bf16* __restrict__ Ob, float* __restrict__ Of, float* __restrict__ Of2,
    bf16* __restrict__ Ob2, int K, int lda_b, int ldb_b) {
  __shared__ char smem[2][24576];
  const int tid = threadIdx.x, lane = tid & 63, wave = tid >> 6;
  const int wm = wave >> 1, wn = wave & 1;
  const int bn = blockIdx.x, bm = blockIdx.y;
  const char* Ab = (const char*)A + (size_t)bm * 128 * lda_b;
  const char* Bb = (const char*)Bw + (size_t)bn * 64 * ldb_b;

  f32x4 acc[4][2] = {};
  const int KT = K >> 6;

  auto stage = [&](int kt, int bi) {
    char* ld = smem[bi];
    int kb = kt * 128;
#pragma unroll
    for (int c2 = 0; c2 < 4; ++c2) {
      int c = wave + c2 * 4;
      stage_rows(Ab, lda_b, kb, c * 8, ld + c * 1024, lane);
    }
#pragma unroll
    for (int c2 = 0; c2 < 2; ++c2) {
      int c = wave + c2 * 4;
      stage_rows(Bb, ldb_b, kb, c * 8, ld + 16384 + c * 1024, lane);
    }
  };

  stage(0, 0);
  __syncthreads();
  for (int kt = 0; kt < KT; ++kt) {
    int cur = kt & 1;
    if (kt + 1 < KT) stage(kt + 1, cur ^ 1);
    const char* lA = smem[cur];
    const char* lB = smem[cur] + 16384;
#pragma unroll
    for (int kh = 0; kh < 2; ++kh) {
      int kk = kh * 32;
      short8 a[4], b[2];
#pragma unroll
      for (int mi = 0; mi < 4; ++mi) a[mi] = frag_ld(lA, wm * 64 + mi * 16, kk, lane, 128);
#pragma unroll
      for (int nj = 0; nj < 2; ++nj) b[nj] = frag_ld(lB, wn * 32 + nj * 16, kk, lane, 128);
#pragma unroll
      for (int mi = 0; mi < 4; ++mi)
#pragma unroll
        for (int nj = 0; nj < 2; ++nj) acc[mi][nj] = MFMA(a[mi], b[nj], acc[mi][nj]);
    }
    __syncthreads();
  }

#pragma unroll
  for (int mi = 0; mi < 4; ++mi)
#pragma unroll
    for (int nj = 0; nj < 2; ++nj) {
      int col = bn * 64 + wn * 32 + nj * 16 + (lane & 15);
      float bc = bias[col];
#pragma unroll
      for (int ii = 0; ii < 4; ++ii) {
        int row = bm * 128 + wm * 64 + mi * 16 + ((lane >> 4) << 2) + ii;
        float v = acc[mi][nj][ii] + bc;
        if constexpr (MODE == 1) {
          v = v > 0.f ? v : 0.2f * v;
          Ob[row * 512 + col] = __float2bfloat16(v);
        } else {
          int d = row >> 10, rr = row & 1023;
          int b = 2 * rr + (col >> 9), j = col & 511;
          bf16 vb = __float2bfloat16(v);
          if (d == 0) {
            Of[b * 512 + j] = v;
            Ob[b * 640 + 128 + j] = vb;
          } else {
            Of2[b * 512 + j] = v;
            Ob2[b * 1024 + 512 + j] = vb;
          }
        }
      }
    }
}

// ------------------------- shared phase device code ------------------------
struct KArgs {
  const bf16* wcat0;
  const bf16* wcat1;
  const bf16* wout;
  const float *bih0, *bhh0, *bih1, *bhh1;
  const float *bv, *bt1, *bmb, *wt2, *bt2;
  bf16 *X0a, *X0b, *X1a, *X1b;
  float *hAfa, *hAfb, *hBfa, *hBfb;
  bf16* f2b;
  int *act, *lens;
  unsigned* bars;  // 512 unsigneds: sub g at [g*32], master at [256]
  float* out;
};

// 2-level monotonic grid barrier. seq = 1-based barrier index.
__device__ __forceinline__ void gsync(unsigned* bars, int g, unsigned seq) {
  __syncthreads();
  if (threadIdx.x == 0) {
    __threadfence();  // release: agent-scope wb so other XCDs see phase writes
    unsigned pos = __hip_atomic_fetch_add(&bars[g * 32], 1u, __ATOMIC_RELAXED,
                                          __HIP_MEMORY_SCOPE_AGENT);
    if ((pos & 63) == 63)
      __hip_atomic_fetch_add(&bars[256], 1u, __ATOMIC_RELAXED, __HIP_MEMORY_SCOPE_AGENT);
    while (__hip_atomic_load(&bars[256], __ATOMIC_RELAXED, __HIP_MEMORY_SCOPE_AGENT) <
           seq * 8u)
      __builtin_amdgcn_s_sleep(2);
    __threadfence();  // acquire: invalidate so we read fresh data
  }
  __syncthreads();
}

template <int KX>
__device__ __forceinline__ void gru_phase(
    char (&smem)[2][20480], int bn, int bm, int lane, int wave,
    const bf16* __restrict__ X, const bf16* __restrict__ Wcat,
    const float* __restrict__ bih, const float* __restrict__ bhh,
    const float* __restrict__ Hpf, const int* __restrict__ act,
    bf16* __restrict__ Fo, int fs, int fo,
    bf16* __restrict__ Hb, int hs, int ho, float* __restrict__ Hf) {
  constexpr int KTOT = KX + 512;
  constexpr int KT = KTOT / 64;
  constexpr int NI = KX / 64;
  constexpr int LDB = KTOT * 2;
  const int wm = wave >> 1, wn = wave & 1;
  const char* Xb = (const char*)X + (size_t)bm * 64 * LDB;
  const char* Wb = (const char*)Wcat;

  f32x4 ar[2] = {}, az[2] = {}, ani[2] = {}, anh[2] = {};

  auto stage = [&](int kt, int bi) {
    char* ld = smem[bi];
    int kb = kt * 128;
    stage_rows(Xb, LDB, kb, wave * 8, ld + wave * 1024, lane);
    stage_rows(Xb, LDB, kb, (wave + 4) * 8, ld + (wave + 4) * 1024, lane);
#pragma unroll
    for (int c2 = 0; c2 < 3; ++c2) {
      int c = wave + c2 * 4;  // 0..11: gate g=c>>2, sub-chunk cr=c&3
      int g = c >> 2, cr = c & 3;
      stage_rows(Wb + (size_t)(g * 512 + bn * 32) * LDB, LDB, kb, cr * 8,
                 ld + 8192 + c * 1024, lane);
    }
  };

  auto body = [&](int kt, f32x4(&an)[2]) {
    int cur = kt & 1;
    if (kt + 1 < KT) stage(kt + 1, cur ^ 1);
    const char* lA = smem[cur];
    const char* lB = smem[cur] + 8192;
#pragma unroll
    for (int kh = 0; kh < 2; ++kh) {
      int kk = kh * 32;
      short8 a0 = frag_ld(lA, wm * 32, kk, lane, 128);
      short8 a1 = frag_ld(lA, wm * 32 + 16, kk, lane, 128);
      short8 br = frag_ld(lB, wn * 16, kk, lane, 128);
      short8 bz = frag_ld(lB + 4096, wn * 16, kk, lane, 128);
      short8 bnn = frag_ld(lB + 8192, wn * 16, kk, lane, 128);
      ar[0] = MFMA(a0, br, ar[0]);
      ar[1] = MFMA(a1, br, ar[1]);
      az[0] = MFMA(a0, bz, az[0]);
      az[1] = MFMA(a1, bz, az[1]);
      an[0] = MFMA(a0, bnn, an[0]);
      an[1] = MFMA(a1, bnn, an[1]);
    }
    __syncthreads();
  };

  stage(0, 0);
  __syncthreads();
  for (int kt = 0; kt < NI; ++kt) body(kt, ani);
  for (int kt = NI; kt < KT; ++kt) body(kt, anh);

  const int colg = bn * 32 + wn * 16 + (lane & 15);
  const float b_r = bih[colg] + bhh[colg];
  const float b_z = bih[512 + colg] + bhh[512 + colg];
  const float bni = bih[1024 + colg];
  const float bnh = bhh[1024 + colg];
#pragma unroll
  for (int mi = 0; mi < 2; ++mi)
#pragma unroll
    for (int ii = 0; ii < 4; ++ii) {
      int row = bm * 64 + wm * 32 + mi * 16 + ((lane >> 4) << 2) + ii;
      float r_ = sigm(ar[mi][ii] + b_r);
      float z_ = sigm(az[mi][ii] + b_z);
      float n_ = tanhf(ani[mi][ii] + bni + r_ * (anh[mi][ii] + bnh));
      float hp = Hpf[row * 512 + colg];
      float f = (1.f - z_) * n_ + z_ * hp;
      Fo[(size_t)row * fs + fo + colg] = __float2bfloat16(f);
      float hn = act[row] ? f : hp;
      Hb[(size_t)row * hs + ho + colg] = __float2bfloat16(hn);
      Hf[row * 512 + colg] = hn;
    }
}

__device__ __forceinline__ void out_phase(
    char (&smem)[2][20480], int og, int lane, int wave, int tid,
    const bf16* __restrict__ F2, const bf16* __restrict__ Wo,
    const float* __restrict__ bv, const float* __restrict__ bt1,
    const float* __restrict__ bm_, const float* __restrict__ wt2,
    const float* __restrict__ bt2,
    int* __restrict__ active, int* __restrict__ lens,
    float* __restrict__ out, int t, int last) {
  char* sA = smem[0];
  float(*red)[68] = (float(*)[68])(smem[1]);
  unsigned* stopf = (unsigned*)(smem[1] + 16 * 68 * 4);
  const int brow = og * 16;

  if (tid < 16) stopf[tid] = 0;

#pragma unroll
  for (int c2 = 0; c2 < 4; ++c2) {
    int c = wave + c2 * 4;
    int l = (lane * 16) ^ ((c & 7) << 4);
    gld16((const char*)F2 + (size_t)(brow + c) * 1024 + l, sA + c * 1024);
  }
  __syncthreads();

  f32x4 acc[5] = {};
#pragma unroll 4
  for (int k0 = 0; k0 < 512; k0 += 32) {
    short8 a = frag_ld(sA, 0, k0, lane, 1024);
#pragma unroll
    for (int nf = 0; nf < 5; ++nf) {
      int col = wave * 80 + nf * 16 + (lane & 15);
      short8 b = *(const short8*)((const char*)Wo + (size_t)col * 1024 +
                                  ((k0 + ((lane >> 4) << 3)) << 1));
      acc[nf] = MFMA(a, b, acc[nf]);
    }
  }

#pragma unroll
  for (int nf = 0; nf < 5; ++nf) {
    int col = wave * 80 + nf * 16 + (lane & 15);
#pragma unroll
    for (int ii = 0; ii < 4; ++ii) {
      int r = ((lane >> 4) << 2) + ii;
      int b = brow + r;
      float v = acc[nf][ii];
      if (col < 128) {
        out[(size_t)b * 16384 + t * 128 + col] = sigm(v + bv[col]);
      } else if (col < 192) {
        float x = v + bt1[col - 128];
        red[r][col - 128] = x > 0.f ? x : 0.2f * x;
      } else {
        float m = v + bm_[col - 192];
        out[OFF_M + (size_t)b * 16384 + t * 128 + (col - 192)] = m;
        if (m >= 0.f) atomicOr(&stopf[r], 1u);
      }
    }
  }
  __syncthreads();
  if (tid < 16) {
    int b = brow + tid;
    float s = bt2[0];
    for (int c = 0; c < 64; ++c) s += red[tid][c] * wt2[c];
    out[OFF_U + (size_t)b * 128 + t] = sigm(s);
    int a = active[b];
    int nl = lens[b] + a;
    lens[b] = nl;
    active[b] = a & (stopf[tid] ? 1 : 0);
    if (last) out[OFF_S + b] = (float)nl;
  }
}

// ------------------------- persistent cooperative kernel -------------------
__global__ __launch_bounds__(256, 2) void decoder_loop(KArgs A) {
  const int blk = blockIdx.x;  // 0..511
  const int tid = threadIdx.x, lane = tid & 63, wave = tid >> 6;
  __shared__ char smem[2][20480];

  // XCD-heuristic row ownership: blk%8 owns bm in [4*(blk%8), 4*(blk%8)+3]
  const int g = blk & 7, j = blk >> 3;
  const int bm = g * 4 + (j & 3);
  const int bn = j >> 2;
  const int og = g * 16 + (blk >> 3);  // valid for blk<128: rows match owner

  const bf16 *X0c = A.X0a, *X1c = A.X1a;
  bf16 *X0n = A.X0b, *X1n = A.X1b;
  const float *hAc = A.hAfa, *hBc = A.hBfa;
  float *hAn = A.hAfb, *hBn = A.hBfb;

  unsigned seq = 0;
  for (int t = 0; t < 128; ++t) {
    // L0: gates = [e|hA] @ wcat0^T ; f1 -> X1c[:,0:512]; hA' -> X0n[:,128:640]
    gru_phase<128>(smem, bn, bm, lane, wave, X0c, A.wcat0, A.bih0, A.bhh0, hAc,
                   A.act, (bf16*)X1c, 1024, 0, X0n, 640, 128, hAn);
    gsync(A.bars, g, ++seq);
    // L1: gates = [f1|hB] @ wcat1^T ; f2 -> f2b; hB' -> X1n[:,512:1024]
    gru_phase<512>(smem, bn, bm, lane, wave, X1c, A.wcat1, A.bih1, A.bhh1, hBc,
                   A.act, A.f2b, 512, 0, X1n, 1024, 512, hBn);
    gsync(A.bars, g, ++seq);
    if (blk < 128)
      out_phase(smem, og, lane, wave, tid, A.f2b, A.wout, A.bv, A.bt1, A.bmb,
                A.wt2, A.bt2, A.act, A.lens, A.out, t, t == 127);
    gsync(A.bars, g, ++seq);
    // swap ping-pong
    const bf16* tx0 = X0c; X0c = X0n; X0n = (bf16*)tx0;
    const bf16* tx1 = X1c; X1c = X1n; X1n = (bf16*)tx1;
    const float* th = hAc; hAc = hAn; hAn = (float*)th;
    const float* tb = hBc; hBc = hBn; hBn = (float*)tb;
  }
}

// ----------------- fallback per-step kernels (R2 path) ---------------------
template <int KX>
__global__ __launch_bounds__(256) void gru_step_k(
    const bf16* X, const bf16* Wcat, const float* bih, const float* bhh,
    const float* Hpf, const int* act, bf16* Fo, int fs, int fo,
    bf16* Hb, int hs, int ho, float* Hf) {
  __shared__ char smem[2][20480];
  gru_phase<KX>(smem, blockIdx.x, blockIdx.y, threadIdx.x & 63, threadIdx.x >> 6,
                X, Wcat, bih, bhh, Hpf, act, Fo, fs, fo, Hb, hs, ho, Hf);
}

__global__ __launch_bounds__(256) void outproj_k(
    const bf16* F2, const bf16* Wo, const float* bv, const float* bt1,
    const float* bm_, const float* wt2, const float* bt2,
    int* active, int* lens, float* out, int t, int last) {
  __shared__ char smem[2][20480];
  out_phase(smem, blockIdx.x, threadIdx.x & 63, threadIdx.x >> 6, threadIdx.x,
            F2, Wo, bv, bt1, bm_, wt2, bt2, active, lens, out, t, last);
}

extern "C" void kernel_launch(void* const* d_in, const int* in_sizes, int n_in,
                              void* d_out, int out_size, void* d_ws, size_t ws_size,
                              hipStream_t stream) {
  const float* e = (const float*)d_in[0];
  const float* fc1w = (const float*)d_in[1];
  const float* fc1b = (const float*)d_in[2];
  const float* fc2w = (const float*)d_in[3];
  const float* fc2b = (const float*)d_in[4];
  const float* wih0 = (const float*)d_in[5];
  const float* whh0 = (const float*)d_in[6];
  const float* bih0 = (const float*)d_in[7];
  const float* bhh0 = (const float*)d_in[8];
  const float* wih1 = (const float*)d_in[9];
  const float* whh1 = (const float*)d_in[10];
  const float* bih1 = (const float*)d_in[11];
  const float* bhh1 = (const float*)d_in[12];
  const float* wv = (const float*)d_in[13];
  const float* bv = (const float*)d_in[14];
  const float* wt1 = (const float*)d_in[15];
  const float* bt1 = (const float*)d_in[16];
  const float* wt2 = (const float*)d_in[17];
  const float* bt2 = (const float*)d_in[18];
  const float* wm = (const float*)d_in[19];
  const float* bmb = (const float*)d_in[20];
  float* out = (float*)d_out;

  char* p = (char*)d_ws;
  auto carve = [&](size_t bytes) {
    char* r = p;
    p += (bytes + 255) & ~(size_t)255;
    return r;
  };
  bf16* X0a = (bf16*)carve((size_t)2048 * 640 * 2);
  bf16* X0b = (bf16*)carve((size_t)2048 * 640 * 2);
  bf16* X1a = (bf16*)carve((size_t)2048 * 1024 * 2);
  bf16* X1b = (bf16*)carve((size_t)2048 * 1024 * 2);
  bf16* wcat0 = (bf16*)carve((size_t)1536 * 640 * 2);
  bf16* wcat1 = (bf16*)carve((size_t)1536 * 1024 * 2);
  float* hAfa = (float*)carve(2048 * 512 * 4);
  float* hAfb = (float*)carve(2048 * 512 * 4);
  float* hBfa = (float*)carve(2048 * 512 * 4);
  float* hBfb = (float*)carve(2048 * 512 * 4);
  bf16* t1_b = (bf16*)carve(2048 * 512 * 2);
  bf16* wfc1b = (bf16*)carve(512 * 128 * 2);
  bf16* wfc2b = (bf16*)carve(1024 * 512 * 2);
  bf16* woutb = (bf16*)carve(320 * 512 * 2);
  bf16* f2b = (bf16*)carve(2048 * 512 * 2);
  int* act = (int*)carve(2048 * 4);
  int* lens = (int*)carve(2048 * 4);
  unsigned* bars = (unsigned*)carve(512 * 4);

  auto cvt = [&](const float* s, bf16* d, int n) {
    cvtk<<<dim3((n + 255) / 256), dim3(256), 0, stream>>>(s, d, n);
  };
  initk<<<dim3(8), dim3(256), 0, stream>>>(act, lens, bars);
  e_fill<<<dim3(1024), dim3(256), 0, stream>>>(e, X0a, X0b);
  catk<<<dim3((1536 * 640 + 255) / 256), dim3(256), 0, stream>>>(wih0, whh0, wcat0, 128, 1536 * 640);
  catk<<<dim3((1536 * 1024 + 255) / 256), dim3(256), 0, stream>>>(wih1, whh1, wcat1, 512, 1536 * 1024);
  cvt(fc1w, wfc1b, 512 * 128);
  cvt(fc2w, wfc2b, 1024 * 512);
  cvt(wv, woutb, 128 * 512);
  cvt(wt1, woutb + 128 * 512, 64 * 512);
  cvt(wm, woutb + 192 * 512, 128 * 512);

  gemm_plain<1><<<dim3(8, 16), dim3(256), 0, stream>>>(
      X0a, wfc1b, fc1b, t1_b, nullptr, nullptr, nullptr, 128, 1280, 256);
  gemm_plain<2><<<dim3(16, 16), dim3(256), 0, stream>>>(
      t1_b, wfc2b, fc2b, X0a, hAfa, hBfa, X1a, 512, 1024, 1024);

  KArgs ka;
  ka.wcat0 = wcat0; ka.wcat1 = wcat1; ka.wout = woutb;
  ka.bih0 = bih0; ka.bhh0 = bhh0; ka.bih1 = bih1; ka.bhh1 = bhh1;
  ka.bv = bv; ka.bt1 = bt1; ka.bmb = bmb; ka.wt2 = wt2; ka.bt2 = bt2;
  ka.X0a = X0a; ka.X0b = X0b; ka.X1a = X1a; ka.X1b = X1b;
  ka.hAfa = hAfa; ka.hAfb = hAfb; ka.hBfa = hBfa; ka.hBfb = hBfb;
  ka.f2b = f2b; ka.act = act; ka.lens = lens; ka.bars = bars; ka.out = out;
  void* params[] = {(void*)&ka};
  hipError_t cerr = hipLaunchCooperativeKernel((const void*)decoder_loop, dim3(512),
                                               dim3(256), params, 0, stream);
  if (cerr != hipSuccess) {
    // Fallback: per-step multi-kernel path (identical numerics).
    const bf16 *X0c = X0a, *X1c = X1a;
    bf16 *X0n = X0b, *X1n = X1b;
    const float *hAc = hAfa, *hBc = hBfa;
    float *hAn = hAfb, *hBn = hBfb;
    for (int t = 0; t < 128; ++t) {
      gru_step_k<128><<<dim3(16, 32), dim3(256), 0, stream>>>(
          X0c, wcat0, bih0, bhh0, hAc, act, (bf16*)X1c, 1024, 0, X0n, 640, 128, hAn);
      gru_step_k<512><<<dim3(16, 32), dim3(256), 0, stream>>>(
          X1c, wcat1, bih1, bhh1, hBc, act, f2b, 512, 0, X1n, 1024, 512, hBn);
      outproj_k<<<dim3(128), dim3(256), 0, stream>>>(
          f2b, woutb, bv, bt1, bmb, wt2, bt2, act, lens, out, t, t == 127);
      const bf16* tx0 = X0c; X0c = X0n; X0n = (bf16*)tx0;
      const bf16* tx1 = X1c; X1c = X1n; X1n = (bf16*)tx1;
      const float* th = hAc; hAc = hAn; hAn = (float*)th;
      const float* tb = hBc; hBc = hBn; hBn = (float*)tb;
    }
  }
}